// Round 8
// baseline (205.273 us; speedup 1.0000x reference)
//
#include <hip/hip_runtime.h>
#include <hip/hip_bf16.h>

typedef __attribute__((ext_vector_type(8))) short short8;
typedef __attribute__((ext_vector_type(4))) float f32x4;
typedef unsigned short ushort_t;
typedef unsigned int uint32;

#define T_DIM   336
#define N_NODES 325
#define O_DIM   96
#define BD      384      // rows per node-group (B*D)
#define ND      975      // N*D
#define XB      327600   // T_DIM * ND
#define KT      96       // K per step
#define NSTEP   4        // K padded to 384
#define MT      128
#define AST     104      // Atile stride (ushorts), mult of 8 -> 16B-aligned b128
#define BST     104      // Btile stride (ushorts)
#define BSEG    10240    // ushorts per (nn,s) packed-B block = 1280*8 (DMA-tail padded)
#define WTO     32256    // 336*96
#define WP_T    120      // staged Wd rows per (nn,s): [t0-12, t0+108)

static __device__ __forceinline__ uint32 pk2bf(float a, float b) {
    union { __hip_bfloat16 h; ushort_t u; } x, y;
    x.h = __float2bfloat16(a); y.h = __float2bfloat16(b);
    return ((uint32)y.u << 16) | x.u;
}

static __device__ __forceinline__ void gload_lds16(const void* g, void* l) {
    __builtin_amdgcn_global_load_lds(
        (const __attribute__((address_space(1))) void*)g,
        (__attribute__((address_space(3))) void*)l, 16, 0, 0);
}

// ---------------------------------------------------------------------------
// Kernel 1: fold moving-average into weights (exact round-3 version).
// ---------------------------------------------------------------------------
__global__ __launch_bounds__(576)
void dlinear_wprep(const float* __restrict__ Ws, const float* __restrict__ bs,
                   const float* __restrict__ Wt, const float* __restrict__ bt,
                   ushort_t* __restrict__ Bpack, float* __restrict__ biasArr)
{
    __shared__ float Wdl[WP_T][O_DIM];     // 46,080 B
    const int nn  = blockIdx.x;
    const int s   = blockIdx.y;
    const int tid = threadIdx.x;
    const int t0  = s * KT;

    const float* wsn = Ws + (size_t)nn * WTO;
    const float* wtn = Wt + (size_t)nn * WTO;

    #pragma unroll
    for (int it = 0; it < 20; ++it) {
        int i = tid + it*576;              // 20*576 = 11520 = 120*96 exact
        int t = i / O_DIM;
        int o = i - t*O_DIM;
        int tg = t0 - 12 + t;
        float v = 0.f;
        if (tg >= 0 && tg < T_DIM) v = wtn[tg*O_DIM + o] - wsn[tg*O_DIM + o];
        Wdl[t][o] = v;
    }
    if (s == 0 && tid < O_DIM)
        biasArr[nn*O_DIM + tid] = bs[nn*O_DIM + tid] + bt[nn*O_DIM + tid];
    __syncthreads();

    const int kc = tid / O_DIM;            // 0..5 (16 k's each)
    const int o  = tid - kc*O_DIM;
    const int k0 = kc * 16;

    float S = 0.f;
    #pragma unroll
    for (int j = 0; j < 25; ++j) S += Wdl[k0 + j][o];

    uint32* bp32 = (uint32*)(Bpack + (size_t)(nn*4 + s) * BSEG + o * BST);
    float prev = 0.f;
    #pragma unroll
    for (int j = 0; j < 16; ++j) {
        const int k = k0 + j;
        const int v = t0 + k;
        float val = 0.f;
        if (v < T_DIM) {
            float V = S;
            if (v == 0) {
                V = 0.f;
                #pragma unroll
                for (int t = 0; t <= 12; ++t) V += (float)(13 - t) * Wdl[12 + t][o];
            } else if (v == T_DIM - 1) {
                V = 0.f;
                #pragma unroll
                for (int t = 0; t <= 12; ++t) V += (float)(t + 1) * Wdl[47 + t][o];
            }
            val = wsn[v*O_DIM + o] + V * (1.0f/25.0f);
        }
        if (j & 1) bp32[k >> 1] = pk2bf(prev, val); else prev = val;
        if (j < 15) S += Wdl[k + 25][o] - Wdl[k][o];
    }
    if (kc == 0) {
        bp32[48] = 0u; bp32[49] = 0u; bp32[50] = 0u; bp32[51] = 0u;
    }
}

// ---------------------------------------------------------------------------
// Kernel 2: bf16 GEMM (exact round-3 version, incl. nontemporal x loads).
// ---------------------------------------------------------------------------
__global__ __launch_bounds__(512, 6)
void dlinear_gemm(const float* __restrict__ x,
                  const ushort_t* __restrict__ Bpack,
                  const float* __restrict__ biasArr,
                  float* __restrict__ Cws)
{
    __shared__ ushort_t Btile[BSEG];
    __shared__ ushort_t Atile[MT][AST];

    const int tid = threadIdx.x;
    const int bid = blockIdx.x;
    const int nn  = bid / 3;
    const int m0  = (bid % 3) * MT;
    const int r_base = nn * BD + m0;

    const int m   = tid & (MT-1);
    const int tb  = (tid >> 7) * 24;          // 24-wide t-span per thread per step
    const int r   = r_base + m;
    const int bI  = r / ND;
    const int rem = r - bI * ND;
    const float* xp = x + (size_t)bI * XB + rem;   // + t*ND

    const ushort_t* bsrc = Bpack + (size_t)nn * (4*BSEG);

    const int wave = tid >> 6;
    const int lane = tid & 63;
    const int wm = wave & 3;
    const int wn = wave >> 2;
    const int a_row0 = wm*32 + (lane & 15);
    const int b_col0 = wn*48 + (lane & 15);
    const int ksub   = (lane >> 4) * 8;

    f32x4 acc[2][3];
    #pragma unroll
    for (int i = 0; i < 2; ++i)
        #pragma unroll
        for (int j = 0; j < 3; ++j)
            acc[i][j] = (f32x4){0.f, 0.f, 0.f, 0.f};

    for (int s = 0; s < NSTEP; ++s) {
        __syncthreads();   // previous step's MFMA reads done; LDS reusable

        // ---- B tile: 20,480 B direct-to-LDS (linear, 16B/lane, full waves only)
        {
            const ushort_t* bs_s = bsrc + (size_t)s * BSEG;
            gload_lds16(bs_s + (size_t)tid*8,        &Btile[tid*8]);
            gload_lds16(bs_s + (size_t)(tid+512)*8,  &Btile[(tid+512)*8]);
            if (tid < 256)
                gload_lds16(bs_s + (size_t)(tid+1024)*8, &Btile[(tid+1024)*8]);
        }

        // ---- A tile: 24 coalesced dword loads/thread, pk-cvt, b64 LDS writes
        const int t0 = s * KT;
        #pragma unroll
        for (int h = 0; h < 2; ++h) {
            float v[12];
            #pragma unroll
            for (int u = 0; u < 12; ++u) {
                int t  = t0 + tb + h*12 + u;
                int tc = t < T_DIM ? t : (T_DIM-1);   // K-pad: garbage x * 0-weight
                v[u] = __builtin_nontemporal_load(&xp[tc * ND]);
            }
            uint32 p[6];
            #pragma unroll
            for (int u = 0; u < 6; ++u) p[u] = pk2bf(v[2*u], v[2*u+1]);
            uint32* arow = (uint32*)&Atile[m][tb + h*12];   // 8B-aligned
            *(uint2*)&arow[0] = make_uint2(p[0], p[1]);
            *(uint2*)&arow[2] = make_uint2(p[2], p[3]);
            *(uint2*)&arow[4] = make_uint2(p[4], p[5]);
        }
        __syncthreads();   // implicit vmcnt(0) drain covers the B DMA

        // ---- MFMA: K=96 per step, 3 chunks of 32
        #pragma unroll
        for (int kc = 0; kc < 3; ++kc) {
            const int k = kc*32 + ksub;
            short8 a0 = *(const short8*)&Atile[a_row0     ][k];
            short8 a1 = *(const short8*)&Atile[a_row0 + 16][k];
            short8 b0 = *(const short8*)&Btile[(b_col0     )*BST + k];
            short8 b1 = *(const short8*)&Btile[(b_col0 + 16)*BST + k];
            short8 b2 = *(const short8*)&Btile[(b_col0 + 32)*BST + k];
            acc[0][0] = __builtin_amdgcn_mfma_f32_16x16x32_bf16(a0, b0, acc[0][0], 0, 0, 0);
            acc[1][0] = __builtin_amdgcn_mfma_f32_16x16x32_bf16(a1, b0, acc[1][0], 0, 0, 0);
            acc[0][1] = __builtin_amdgcn_mfma_f32_16x16x32_bf16(a0, b1, acc[0][1], 0, 0, 0);
            acc[1][1] = __builtin_amdgcn_mfma_f32_16x16x32_bf16(a1, b1, acc[1][1], 0, 0, 0);
            acc[0][2] = __builtin_amdgcn_mfma_f32_16x16x32_bf16(a0, b2, acc[0][2], 0, 0, 0);
            acc[1][2] = __builtin_amdgcn_mfma_f32_16x16x32_bf16(a1, b2, acc[1][2], 0, 0, 0);
        }
    }

    // ---- epilogue: C/D map col=lane&15, row=(lane>>4)*4+j
    float* Cbase = Cws + (size_t)r_base * O_DIM;
    const float* bfp = biasArr + nn * O_DIM;
    const int rsub = (lane >> 4) * 4;
    #pragma unroll
    for (int fm = 0; fm < 2; ++fm) {
        #pragma unroll
        for (int fn = 0; fn < 3; ++fn) {
            const int col = b_col0 + fn*16;
            const float bv = bfp[col];
            #pragma unroll
            for (int j = 0; j < 4; ++j) {
                const int rowm = wm*32 + fm*16 + rsub + j;
                Cbase[rowm*O_DIM + col] = acc[fm][fn][j] + bv;
            }
        }
    }
}

// ---------------------------------------------------------------------------
// Kernel 3: layout fixup (exact round-3 version).
// ---------------------------------------------------------------------------
__global__ __launch_bounds__(256)
void dlinear_out(const float* __restrict__ Cws, float* __restrict__ out)
{
    __shared__ float tile[65][97];
    const int m   = blockIdx.x;           // 0..383
    const int nn0 = blockIdx.y * 65;      // 325 = 5*65
    const int tid = threadIdx.x;

    for (int idx = tid; idx < 65*O_DIM; idx += 256) {
        int nni = idx / O_DIM;
        int o   = idx - nni*O_DIM;
        tile[nni][o] = Cws[(size_t)((nn0 + nni)*BD + m)*O_DIM + o];
    }
    __syncthreads();
    const int b = m / 3;
    const int g = m - b*3;
    float* obase = out + (size_t)b*93600 + g*N_NODES + nn0;
    for (int idx = tid; idx < 65*O_DIM; idx += 256) {
        int o   = idx / 65;
        int nni = idx - o*65;
        obase[o*ND + nni] = tile[nni][o];
    }
}

extern "C" void kernel_launch(void* const* d_in, const int* in_sizes, int n_in,
                              void* d_out, int out_size, void* d_ws, size_t ws_size,
                              hipStream_t stream)
{
    const float* x  = (const float*)d_in[0];
    const float* Ws = (const float*)d_in[1];
    const float* bs = (const float*)d_in[2];
    const float* Wt = (const float*)d_in[3];
    const float* bt = (const float*)d_in[4];
    float* out = (float*)d_out;
    float* Cws = (float*)d_ws;                     // 124800*96*4 = 47.9 MB

    ushort_t* Bpack  = (ushort_t*)d_out;
    float*    biasAr = (float*)d_out + 6656000;    // = 325*4*10240/2

    // ATTRIBUTION PROBE: gemm and out launched twice (idempotent rewrites of
    // Cws / d_out). Both gemm launches run BEFORE out overwrites the Bpack
    // region of d_out, so every launch sees identical inputs -> deterministic.
    // T - 133.4us (round-3 baseline) ~= gemm + out marginal cost.
    dlinear_wprep<<<dim3(N_NODES, 4), dim3(576), 0, stream>>>(Ws, bs, Wt, bt, Bpack, biasAr);
    dlinear_gemm <<<dim3(975),        dim3(512), 0, stream>>>(x, Bpack, biasAr, Cws);
    dlinear_gemm <<<dim3(975),        dim3(512), 0, stream>>>(x, Bpack, biasAr, Cws);
    dlinear_out  <<<dim3(384, 5),     dim3(256), 0, stream>>>(Cws, out);
    dlinear_out  <<<dim3(384, 5),     dim3(256), 0, stream>>>(Cws, out);
}

// Round 9
// 112.493 us; speedup vs baseline: 1.8248x; 1.8248x over previous
//
#include <hip/hip_runtime.h>
#include <hip/hip_bf16.h>

typedef __attribute__((ext_vector_type(8))) short short8;
typedef __attribute__((ext_vector_type(4))) float f32x4;
typedef unsigned short ushort_t;
typedef unsigned int uint32;

#define T_DIM   336
#define N_NODES 325
#define O_DIM   96
#define BD      384      // rows per node-group (B*D)
#define ND      975      // N*D
#define XB      327600   // T_DIM * ND
#define KT      96       // K per step
#define NSTEP   4        // K padded to 384
#define MT      128
#define AST     104      // Atile stride (ushorts), mult of 8 -> 16B-aligned b128
#define BST     104      // Btile stride (ushorts)
#define BSEG    10240    // ushorts per (nn,s) packed-B block = 1280*8 (DMA-tail padded)
#define WTO     32256    // 336*96
#define WP_T    120      // staged Wd rows per (nn,s): [t0-12, t0+108)

static __device__ __forceinline__ uint32 pk2bf(float a, float b) {
    union { __hip_bfloat16 h; ushort_t u; } x, y;
    x.h = __float2bfloat16(a); y.h = __float2bfloat16(b);
    return ((uint32)y.u << 16) | x.u;
}
static __device__ __forceinline__ ushort_t f2bf(float f) {
    union { __hip_bfloat16 h; ushort_t u; } cv;
    cv.h = __float2bfloat16(f);
    return cv.u;
}
static __device__ __forceinline__ float bf2f(ushort_t u) {
    union { ushort_t u; __hip_bfloat16 h; } cv;
    cv.u = u;
    return __bfloat162float(cv.h);
}

static __device__ __forceinline__ void gload_lds16(const void* g, void* l) {
    __builtin_amdgcn_global_load_lds(
        (const __attribute__((address_space(1))) void*)g,
        (__attribute__((address_space(3))) void*)l, 16, 0, 0);
}

// ---------------------------------------------------------------------------
// Kernel 1 (v2): fold moving-average into weights.
// Fixes vs round-3: (a) 16 wsn loads hoisted into regs (was a serial
// L2-latency chain in the j-loop); (b) output staged in LDS Bout and copied
// linearly (coalesced 64B-line writes; Bout layout == Bpack layout);
// (c) Wd staged bf16 (LDS 43KB -> 3 blocks/CU).
// ---------------------------------------------------------------------------
__global__ __launch_bounds__(576, 7)
void dlinear_wprep(const float* __restrict__ Ws, const float* __restrict__ bs,
                   const float* __restrict__ Wt, const float* __restrict__ bt,
                   ushort_t* __restrict__ Bpack, float* __restrict__ biasArr)
{
    __shared__ ushort_t Wdl[WP_T][O_DIM];    // 23,040 B (bf16 Wd rows t0-12..t0+107)
    __shared__ ushort_t Bout[O_DIM * BST];   // 19,968 B, layout == Bpack block

    const int nn  = blockIdx.x;
    const int s   = blockIdx.y;
    const int tid = threadIdx.x;
    const int t0  = s * KT;

    const float* wsn = Ws + (size_t)nn * WTO;
    const float* wtn = Wt + (size_t)nn * WTO;

    // stage Wd rows: o fixed per thread (576 = 6*96), t = tid/96 + 6*it
    {
        const int o   = tid % O_DIM;
        const int tA  = tid / O_DIM;
        #pragma unroll
        for (int it = 0; it < 20; ++it) {
            int t  = tA + it * 6;
            int tg = t0 - 12 + t;
            float v = 0.f;
            if (tg >= 0 && tg < T_DIM) v = wtn[tg*O_DIM + o] - wsn[tg*O_DIM + o];
            Wdl[t][o] = f2bf(v);
        }
    }
    if (s == 0 && tid < O_DIM)
        biasArr[nn*O_DIM + tid] = bs[nn*O_DIM + tid] + bt[nn*O_DIM + tid];
    __syncthreads();

    const int kc = tid / O_DIM;            // 0..5 (16 k's each)
    const int o  = tid - kc*O_DIM;
    const int k0 = kc * 16;

    // hoisted Ws values for this thread's 16 outputs (independent, batched)
    float wsv[16];
    #pragma unroll
    for (int j = 0; j < 16; ++j) {
        int vv = t0 + k0 + j;
        wsv[j] = (vv < T_DIM) ? wsn[vv*O_DIM + o] : 0.f;
    }

    float S = 0.f;
    #pragma unroll
    for (int j = 0; j < 25; ++j) S += bf2f(Wdl[k0 + j][o]);

    uint32* bo32 = (uint32*)(Bout + o * BST);
    float prev = 0.f;
    #pragma unroll
    for (int j = 0; j < 16; ++j) {
        const int k = k0 + j;
        const int v = t0 + k;
        float val = 0.f;
        if (v < T_DIM) {
            float V = S;
            if (v == 0) {                  // edge multiplicity 13-t, t in [0,12]
                V = 0.f;
                #pragma unroll
                for (int t = 0; t <= 12; ++t) V += (float)(13 - t) * bf2f(Wdl[12 + t][o]);
            } else if (v == T_DIM - 1) {   // edge multiplicity t-322, t in [323,335]
                V = 0.f;
                #pragma unroll
                for (int t = 0; t <= 12; ++t) V += (float)(t + 1) * bf2f(Wdl[47 + t][o]);
            }
            val = wsv[j] + V * (1.0f/25.0f);
        }
        if (j & 1) bo32[k >> 1] = pk2bf(prev, val); else prev = val;
        if (j < 15) S += bf2f(Wdl[k + 25][o]) - bf2f(Wdl[k][o]);
    }
    __syncthreads();

    // linear coalesced copy Bout -> Bpack (4992 dwords; k-pad cols are
    // copied as-is -- gemm's MFMA never reads k >= 96)
    {
        const uint32* src = (const uint32*)Bout;
        uint32* dst = (uint32*)(Bpack + (size_t)(nn*4 + s) * BSEG);
        for (int d = tid; d < (O_DIM*BST)/2; d += 576)
            dst[d] = src[d];
    }
}

// ---------------------------------------------------------------------------
// Kernel 2: bf16 GEMM (exact round-3 version, incl. nontemporal x loads).
// ---------------------------------------------------------------------------
__global__ __launch_bounds__(512, 6)
void dlinear_gemm(const float* __restrict__ x,
                  const ushort_t* __restrict__ Bpack,
                  const float* __restrict__ biasArr,
                  float* __restrict__ Cws)
{
    __shared__ ushort_t Btile[BSEG];
    __shared__ ushort_t Atile[MT][AST];

    const int tid = threadIdx.x;
    const int bid = blockIdx.x;
    const int nn  = bid / 3;
    const int m0  = (bid % 3) * MT;
    const int r_base = nn * BD + m0;

    const int m   = tid & (MT-1);
    const int tb  = (tid >> 7) * 24;          // 24-wide t-span per thread per step
    const int r   = r_base + m;
    const int bI  = r / ND;
    const int rem = r - bI * ND;
    const float* xp = x + (size_t)bI * XB + rem;   // + t*ND

    const ushort_t* bsrc = Bpack + (size_t)nn * (4*BSEG);

    const int wave = tid >> 6;
    const int lane = tid & 63;
    const int wm = wave & 3;
    const int wn = wave >> 2;
    const int a_row0 = wm*32 + (lane & 15);
    const int b_col0 = wn*48 + (lane & 15);
    const int ksub   = (lane >> 4) * 8;

    f32x4 acc[2][3];
    #pragma unroll
    for (int i = 0; i < 2; ++i)
        #pragma unroll
        for (int j = 0; j < 3; ++j)
            acc[i][j] = (f32x4){0.f, 0.f, 0.f, 0.f};

    for (int s = 0; s < NSTEP; ++s) {
        __syncthreads();   // previous step's MFMA reads done; LDS reusable

        // ---- B tile: 20,480 B direct-to-LDS (linear, 16B/lane, full waves only)
        {
            const ushort_t* bs_s = bsrc + (size_t)s * BSEG;
            gload_lds16(bs_s + (size_t)tid*8,        &Btile[tid*8]);
            gload_lds16(bs_s + (size_t)(tid+512)*8,  &Btile[(tid+512)*8]);
            if (tid < 256)
                gload_lds16(bs_s + (size_t)(tid+1024)*8, &Btile[(tid+1024)*8]);
        }

        // ---- A tile: 24 coalesced dword loads/thread, pk-cvt, b64 LDS writes
        const int t0 = s * KT;
        #pragma unroll
        for (int h = 0; h < 2; ++h) {
            float v[12];
            #pragma unroll
            for (int u = 0; u < 12; ++u) {
                int t  = t0 + tb + h*12 + u;
                int tc = t < T_DIM ? t : (T_DIM-1);   // K-pad: garbage x * 0-weight
                v[u] = __builtin_nontemporal_load(&xp[tc * ND]);
            }
            uint32 p[6];
            #pragma unroll
            for (int u = 0; u < 6; ++u) p[u] = pk2bf(v[2*u], v[2*u+1]);
            uint32* arow = (uint32*)&Atile[m][tb + h*12];   // 8B-aligned
            *(uint2*)&arow[0] = make_uint2(p[0], p[1]);
            *(uint2*)&arow[2] = make_uint2(p[2], p[3]);
            *(uint2*)&arow[4] = make_uint2(p[4], p[5]);
        }
        __syncthreads();   // implicit vmcnt(0) drain covers the B DMA

        // ---- MFMA: K=96 per step, 3 chunks of 32
        #pragma unroll
        for (int kc = 0; kc < 3; ++kc) {
            const int k = kc*32 + ksub;
            short8 a0 = *(const short8*)&Atile[a_row0     ][k];
            short8 a1 = *(const short8*)&Atile[a_row0 + 16][k];
            short8 b0 = *(const short8*)&Btile[(b_col0     )*BST + k];
            short8 b1 = *(const short8*)&Btile[(b_col0 + 16)*BST + k];
            short8 b2 = *(const short8*)&Btile[(b_col0 + 32)*BST + k];
            acc[0][0] = __builtin_amdgcn_mfma_f32_16x16x32_bf16(a0, b0, acc[0][0], 0, 0, 0);
            acc[1][0] = __builtin_amdgcn_mfma_f32_16x16x32_bf16(a1, b0, acc[1][0], 0, 0, 0);
            acc[0][1] = __builtin_amdgcn_mfma_f32_16x16x32_bf16(a0, b1, acc[0][1], 0, 0, 0);
            acc[1][1] = __builtin_amdgcn_mfma_f32_16x16x32_bf16(a1, b1, acc[1][1], 0, 0, 0);
            acc[0][2] = __builtin_amdgcn_mfma_f32_16x16x32_bf16(a0, b2, acc[0][2], 0, 0, 0);
            acc[1][2] = __builtin_amdgcn_mfma_f32_16x16x32_bf16(a1, b2, acc[1][2], 0, 0, 0);
        }
    }

    // ---- epilogue: C/D map col=lane&15, row=(lane>>4)*4+j
    float* Cbase = Cws + (size_t)r_base * O_DIM;
    const float* bfp = biasArr + nn * O_DIM;
    const int rsub = (lane >> 4) * 4;
    #pragma unroll
    for (int fm = 0; fm < 2; ++fm) {
        #pragma unroll
        for (int fn = 0; fn < 3; ++fn) {
            const int col = b_col0 + fn*16;
            const float bv = bfp[col];
            #pragma unroll
            for (int j = 0; j < 4; ++j) {
                const int rowm = wm*32 + fm*16 + rsub + j;
                Cbase[rowm*O_DIM + col] = acc[fm][fn][j] + bv;
            }
        }
    }
}

// ---------------------------------------------------------------------------
// Kernel 3: layout fixup (exact round-3 version).
// ---------------------------------------------------------------------------
__global__ __launch_bounds__(256)
void dlinear_out(const float* __restrict__ Cws, float* __restrict__ out)
{
    __shared__ float tile[65][97];
    const int m   = blockIdx.x;           // 0..383
    const int nn0 = blockIdx.y * 65;      // 325 = 5*65
    const int tid = threadIdx.x;

    for (int idx = tid; idx < 65*O_DIM; idx += 256) {
        int nni = idx / O_DIM;
        int o   = idx - nni*O_DIM;
        tile[nni][o] = Cws[(size_t)((nn0 + nni)*BD + m)*O_DIM + o];
    }
    __syncthreads();
    const int b = m / 3;
    const int g = m - b*3;
    float* obase = out + (size_t)b*93600 + g*N_NODES + nn0;
    for (int idx = tid; idx < 65*O_DIM; idx += 256) {
        int o   = idx / 65;
        int nni = idx - o*65;
        obase[o*ND + nni] = tile[nni][o];
    }
}

extern "C" void kernel_launch(void* const* d_in, const int* in_sizes, int n_in,
                              void* d_out, int out_size, void* d_ws, size_t ws_size,
                              hipStream_t stream)
{
    const float* x  = (const float*)d_in[0];
    const float* Ws = (const float*)d_in[1];
    const float* bs = (const float*)d_in[2];
    const float* Wt = (const float*)d_in[3];
    const float* bt = (const float*)d_in[4];
    float* out = (float*)d_out;
    float* Cws = (float*)d_ws;                     // 124800*96*4 = 47.9 MB

    // Packed bf16 weights + bias live in the d_out tail (26.6 MB + 122 KB of
    // 45.7 MB). Final transpose overwrites all of d_out; Bpack regenerated
    // every call => deterministic replays.
    ushort_t* Bpack  = (ushort_t*)d_out;
    float*    biasAr = (float*)d_out + 6656000;    // = 325*4*10240/2

    dlinear_wprep<<<dim3(N_NODES, 4), dim3(576), 0, stream>>>(Ws, bs, Wt, bt, Bpack, biasAr);
    dlinear_gemm <<<dim3(975),        dim3(512), 0, stream>>>(x, Bpack, biasAr, Cws);
    dlinear_out  <<<dim3(384, 5),     dim3(256), 0, stream>>>(Cws, out);
}